// Round 3
// baseline (108.760 us; speedup 1.0000x reference)
//
#include <hip/hip_runtime.h>

// ChebGraphConv as ONE flat GEMM with K=192 over contiguous rows r = bt*1024+n:
//   out[r][o] = sum_{k,c} (d_k[n(r)] * x[r][c]) * Theta[k][c][o] + sum_k bias[k][o]
// R3: W-frags hoisted to registers (no in-loop LDS/barriers), swapped MFMA
// operands so D holds consecutive-o per lane -> dwordx4 stores.
// B=32,T=24,N=1024 -> 786432 rows. C_IN=C_OUT=64, K_cheb=3.

#define NNODES 1024
#define ROWS_PER_BLOCK 256
#define NBLOCKS 3072          // 786432 / 256
#define ITERS 4               // 256 rows / (4 waves * 16 rows)

typedef __attribute__((ext_vector_type(8))) short  short8;  // 8 x bf16 MFMA A/B frag
typedef __attribute__((ext_vector_type(4))) float  f32x4;   // MFMA C/D frag

// round-to-nearest-even f32 -> bf16 bits
__device__ __forceinline__ unsigned short f2bf(float f) {
    union { float f; unsigned u; } v; v.f = f;
    unsigned r = v.u + 0x7FFFu + ((v.u >> 16) & 1u);
    return (unsigned short)(r >> 16);
}

__global__ __launch_bounds__(256) void cheb_v3(
    const float* __restrict__ x,      // [786432 * 64]
    const float* __restrict__ Tks,    // [3 * 1024 * 1024]
    const float* __restrict__ Theta,  // [3 * 64 * 64]  k*4096 + c*64 + o
    const float* __restrict__ bias,   // [3 * 64]
    float* __restrict__ out)          // [786432 * 64]
{
    // WT[k][o][c] = bf16(Theta[k][c][o]); pad 72 (reads happen ONCE per wave,
    // conflict cost negligible). d4: per-row diag scales. bsum: summed bias.
    __shared__ __align__(16) unsigned short WT[3][64][72];
    __shared__ __align__(16) float d4[ROWS_PER_BLOCK][4];
    __shared__ __align__(16) float bsum[64];

    const int tid = threadIdx.x;
    const int rowbase = blockIdx.x * ROWS_PER_BLOCK;

    // ---- stage WT (transpose Theta into LDS as bf16), vectorized over o ----
    for (int idx = tid; idx < 3 * 64 * 16; idx += 256) {
        const int k   = idx >> 10;
        const int rem = idx & 1023;
        const int c   = rem >> 4;
        const int og  = (rem & 15) << 2;
        const f32x4 th = *reinterpret_cast<const f32x4*>(Theta + k * 4096 + c * 64 + og);
        WT[k][og + 0][c] = f2bf(th[0]);
        WT[k][og + 1][c] = f2bf(th[1]);
        WT[k][og + 2][c] = f2bf(th[2]);
        WT[k][og + 3][c] = f2bf(th[3]);
    }
    // ---- stage diag scales for this block's rows (1 row per thread) ----
    {
        const int r = tid;
        const int n = (rowbase + r) & (NNODES - 1);
        const size_t diag = (size_t)n * (NNODES + 1);
        f32x4 v;
        v[0] = Tks[diag];
        v[1] = Tks[(size_t)NNODES * NNODES + diag];
        v[2] = Tks[(size_t)2 * NNODES * NNODES + diag];
        v[3] = 0.0f;
        *reinterpret_cast<f32x4*>(&d4[r][0]) = v;
    }
    if (tid < 64) bsum[tid] = bias[tid] + bias[64 + tid] + bias[128 + tid];
    __syncthreads();

    const int wave = tid >> 6;
    const int lane = tid & 63;
    const int lrow = lane & 15;   // A row (=o) / B col (=bt-row) / D col (=bt-row)
    const int lgrp = lane >> 4;   // frag k-subgroup / D o-subgroup

    // ---- hoist all 24 W-frags (loop-invariant) into registers ----
    // A-operand (W^T): row = o = nb*16+lrow, k = c = kc*64 + h*32 + lgrp*8 + j
    short8 wf[3][2][4];
    #pragma unroll
    for (int kc = 0; kc < 3; ++kc)
        #pragma unroll
        for (int h = 0; h < 2; ++h)
            #pragma unroll
            for (int nb = 0; nb < 4; ++nb)
                wf[kc][h][nb] = *reinterpret_cast<const short8*>(
                    &WT[kc][nb * 16 + lrow][h * 32 + lgrp * 8]);

    // bias frag: o = nb*16 + lgrp*4 + j  (matches D layout below)
    f32x4 bs4[4];
    #pragma unroll
    for (int nb = 0; nb < 4; ++nb)
        bs4[nb] = *reinterpret_cast<const f32x4*>(&bsum[nb * 16 + lgrp * 4]);

    #pragma unroll 1
    for (int it = 0; it < ITERS; ++it) {
        const int lr = it * 64 + wave * 16 + lrow;    // this lane's bt-row (local)
        const float* xrow = x + (size_t)(rowbase + lr) * 64;

        // B-operand (xs^T): col = row lrow, k = kc*64 + h*32 + lgrp*8 + j
        const f32x4 x0 = *reinterpret_cast<const f32x4*>(xrow + lgrp * 8);
        const f32x4 x1 = *reinterpret_cast<const f32x4*>(xrow + lgrp * 8 + 4);
        const f32x4 x2 = *reinterpret_cast<const f32x4*>(xrow + 32 + lgrp * 8);
        const f32x4 x3 = *reinterpret_cast<const f32x4*>(xrow + 32 + lgrp * 8 + 4);

        const f32x4 dv = *reinterpret_cast<const f32x4*>(&d4[lr][0]);  // broadcast-free

        short8 xf[3][2];
        #pragma unroll
        for (int kc = 0; kc < 3; ++kc) {
            const float dk = dv[kc];
            #pragma unroll
            for (int j = 0; j < 4; ++j) {
                xf[kc][0][j]     = (short)f2bf(dk * x0[j]);
                xf[kc][0][4 + j] = (short)f2bf(dk * x1[j]);
                xf[kc][1][j]     = (short)f2bf(dk * x2[j]);
                xf[kc][1][4 + j] = (short)f2bf(dk * x3[j]);
            }
        }

        f32x4 acc[4] = {f32x4{0,0,0,0}, f32x4{0,0,0,0}, f32x4{0,0,0,0}, f32x4{0,0,0,0}};
        #pragma unroll
        for (int kc = 0; kc < 3; ++kc)
            #pragma unroll
            for (int h = 0; h < 2; ++h)
                #pragma unroll
                for (int nb = 0; nb < 4; ++nb)
                    acc[nb] = __builtin_amdgcn_mfma_f32_16x16x32_bf16(
                        wf[kc][h][nb], xf[kc][h], acc[nb], 0, 0, 0);

        // D' = (x*W)^T: lane reg j -> out[row = lrow-row][o = nb*16 + lgrp*4 + j]
        // -> per-lane contiguous 4 floats: dwordx4 stores, 64B segments per instr
        float* orow = out + (size_t)(rowbase + lr) * 64;
        #pragma unroll
        for (int nb = 0; nb < 4; ++nb) {
            f32x4 o4;
            #pragma unroll
            for (int j = 0; j < 4; ++j) o4[j] = acc[nb][j] + bs4[nb][j];
            *reinterpret_cast<f32x4*>(orow + nb * 16 + lgrp * 4) = o4;
        }
    }
}

extern "C" void kernel_launch(void* const* d_in, const int* in_sizes, int n_in,
                              void* d_out, int out_size, void* d_ws, size_t ws_size,
                              hipStream_t stream) {
    const float* x     = (const float*)d_in[0];
    const float* Tks   = (const float*)d_in[1];
    const float* Theta = (const float*)d_in[2];
    const float* bias  = (const float*)d_in[3];
    float* out = (float*)d_out;

    hipLaunchKernelGGL(cheb_v3, dim3(NBLOCKS), dim3(256), 0, stream,
                       x, Tks, Theta, bias, out);
}

// Round 4
// 104.652 us; speedup vs baseline: 1.0393x; 1.0393x over previous
//
#include <hip/hip_runtime.h>

// ChebGraphConv as ONE flat GEMM (K=192) over contiguous rows r = bt*1024+n:
//   out[r][o] = sum_{k,c} (d_k[n(r)] * x[r][c]) * Theta[k][c][o] + sum_k bias[k][o]
// R4: two-kernel design.
//  K1 (cheb_prep): builds in d_ws a fragment-linear bf16 W image (24 frags x 1KB,
//    so each wave reads its MFMA A-operand with ONE coalesced dwordx4), the
//    summed bias, and dvec[n] = {d0,d1,d2,0}.
//  K2 (cheb_main): no LDS, no barriers; depth-2 software-pipelined x loads;
//    swapped MFMA (W as A, x as B) so D holds 4 consecutive o -> dwordx4 stores.
// B=32,T=24,N=1024 -> 786432 rows. C_IN=C_OUT=64, K_cheb=3.

#define NNODES 1024
#define ROWS_PER_BLOCK 256
#define NBLOCKS 3072            // 786432 / 256

// ws layout (40.25 KB total)
#define WS_W  0                 // 24 frags * 64 lanes * 16B = 24 KB (bf16)
#define WS_BS (24 * 1024)       // 64 * f32 summed bias
#define WS_DV (24 * 1024 + 256) // 1024 * f32x4 {d0,d1,d2,0}

typedef __attribute__((ext_vector_type(8))) short  short8;  // 8 x bf16 MFMA frag
typedef __attribute__((ext_vector_type(4))) float  f32x4;   // MFMA C/D frag

// round-to-nearest-even f32 -> bf16 bits
__device__ __forceinline__ unsigned short f2bf(float f) {
    union { float f; unsigned u; } v; v.f = f;
    unsigned r = v.u + 0x7FFFu + ((v.u >> 16) & 1u);
    return (unsigned short)(r >> 16);
}

__global__ void cheb_prep(const float* __restrict__ Tks,
                          const float* __restrict__ Theta,
                          const float* __restrict__ bias,
                          unsigned char* __restrict__ ws) {
    const int b = blockIdx.x;
    const int l = threadIdx.x;   // 64 threads
    if (b < 24) {
        // frag f = (kc*2+h)*4 + nb ; lane l holds W^T row o = nb*16+(l&15),
        // k-slice c = h*32 + (l>>4)*8 + j, j=0..7  (A-operand layout, 16x16x32)
        const int kc = b >> 3, h = (b >> 2) & 1, nb = b & 3;
        const int o  = nb * 16 + (l & 15);
        const int cb = h * 32 + (l >> 4) * 8;
        unsigned short* dst = (unsigned short*)(ws + WS_W) + ((size_t)b * 64 + l) * 8;
        #pragma unroll
        for (int j = 0; j < 8; ++j)
            dst[j] = f2bf(Theta[kc * 4096 + (cb + j) * 64 + o]);
    } else if (b < 40) {
        const int n = (b - 24) * 64 + l;
        const size_t dg = (size_t)n * (NNODES + 1);
        f32x4 v;
        v[0] = Tks[dg];
        v[1] = Tks[(size_t)NNODES * NNODES + dg];
        v[2] = Tks[(size_t)2 * NNODES * NNODES + dg];
        v[3] = 0.0f;
        *((f32x4*)(ws + WS_DV) + n) = v;
    } else {
        float* bs = (float*)(ws + WS_BS);
        bs[l] = bias[l] + bias[64 + l] + bias[128 + l];
    }
}

__global__ __launch_bounds__(256) void cheb_main(
    const float* __restrict__ x,          // [786432 * 64]
    const unsigned char* __restrict__ ws,
    float* __restrict__ out)              // [786432 * 64]
{
    const int tid  = threadIdx.x;
    const int wave = tid >> 6;
    const int lane = tid & 63;
    const int lrow = lane & 15;   // B col (= bt-row) / D col
    const int lgrp = lane >> 4;   // frag k-subgroup / D o-subgroup
    const int rowbase = blockIdx.x * ROWS_PER_BLOCK;
    const int laneoff = wave * 16 + lrow;

    const unsigned short* wimg = (const unsigned short*)(ws + WS_W);
    const float*          bsum = (const float*)(ws + WS_BS);
    const f32x4*          dvec = (const f32x4*)(ws + WS_DV);

    // ---- per-wave constants: 24 W-frags (coalesced dwordx4, L1/L2-hot) ----
    short8 wf[3][2][4];
    #pragma unroll
    for (int kc = 0; kc < 3; ++kc)
        #pragma unroll
        for (int h = 0; h < 2; ++h)
            #pragma unroll
            for (int nb = 0; nb < 4; ++nb)
                wf[kc][h][nb] = *(const short8*)(
                    wimg + ((size_t)(((kc * 2 + h) * 4 + nb) * 64 + lane)) * 8);

    f32x4 bs4[4];
    #pragma unroll
    for (int nb = 0; nb < 4; ++nb)
        bs4[nb] = *(const f32x4*)(bsum + nb * 16 + lgrp * 4);

#define LOADX(IT, X0, X1, X2, X3, DV) do {                                   \
        const int lr_ = (IT) * 64 + laneoff;                                 \
        const float* xr_ = x + (size_t)(rowbase + lr_) * 64;                 \
        X0 = *(const f32x4*)(xr_ + lgrp * 8);                                \
        X1 = *(const f32x4*)(xr_ + lgrp * 8 + 4);                            \
        X2 = *(const f32x4*)(xr_ + 32 + lgrp * 8);                           \
        X3 = *(const f32x4*)(xr_ + 32 + lgrp * 8 + 4);                       \
        DV = dvec[(rowbase + lr_) & (NNODES - 1)];                           \
    } while (0)

#define COMPUTE(IT, X0, X1, X2, X3, DV) do {                                 \
        short8 xf[3][2];                                                     \
        _Pragma("unroll")                                                    \
        for (int kc = 0; kc < 3; ++kc) {                                     \
            const float dk = DV[kc];                                         \
            _Pragma("unroll")                                                \
            for (int j = 0; j < 4; ++j) {                                    \
                xf[kc][0][j]     = (short)f2bf(dk * X0[j]);                  \
                xf[kc][0][4 + j] = (short)f2bf(dk * X1[j]);                  \
                xf[kc][1][j]     = (short)f2bf(dk * X2[j]);                  \
                xf[kc][1][4 + j] = (short)f2bf(dk * X3[j]);                  \
            }                                                                \
        }                                                                    \
        f32x4 acc[4] = {f32x4{0,0,0,0}, f32x4{0,0,0,0},                      \
                        f32x4{0,0,0,0}, f32x4{0,0,0,0}};                     \
        _Pragma("unroll")                                                    \
        for (int kc = 0; kc < 3; ++kc)                                       \
            _Pragma("unroll")                                                \
            for (int h = 0; h < 2; ++h)                                      \
                _Pragma("unroll")                                            \
                for (int nb = 0; nb < 4; ++nb)                               \
                    acc[nb] = __builtin_amdgcn_mfma_f32_16x16x32_bf16(       \
                        wf[kc][h][nb], xf[kc][h], acc[nb], 0, 0, 0);         \
        float* orow = out + (size_t)(rowbase + (IT) * 64 + laneoff) * 64;    \
        _Pragma("unroll")                                                    \
        for (int nb = 0; nb < 4; ++nb) {                                     \
            f32x4 o4;                                                        \
            _Pragma("unroll")                                                \
            for (int j = 0; j < 4; ++j) o4[j] = acc[nb][j] + bs4[nb][j];     \
            *(f32x4*)(orow + nb * 16 + lgrp * 4) = o4;                       \
        }                                                                    \
    } while (0)

    // ---- depth-2 software pipeline over ITERS=4 (static names, no arrays) ----
    f32x4 xa0, xa1, xa2, xa3, da;
    f32x4 xb0, xb1, xb2, xb3, db;

    LOADX(0, xa0, xa1, xa2, xa3, da);
    LOADX(1, xb0, xb1, xb2, xb3, db);
    COMPUTE(0, xa0, xa1, xa2, xa3, da);
    LOADX(2, xa0, xa1, xa2, xa3, da);
    COMPUTE(1, xb0, xb1, xb2, xb3, db);
    LOADX(3, xb0, xb1, xb2, xb3, db);
    COMPUTE(2, xa0, xa1, xa2, xa3, da);
    COMPUTE(3, xb0, xb1, xb2, xb3, db);

#undef LOADX
#undef COMPUTE
}

extern "C" void kernel_launch(void* const* d_in, const int* in_sizes, int n_in,
                              void* d_out, int out_size, void* d_ws, size_t ws_size,
                              hipStream_t stream) {
    const float* x     = (const float*)d_in[0];
    const float* Tks   = (const float*)d_in[1];
    const float* Theta = (const float*)d_in[2];
    const float* bias  = (const float*)d_in[3];
    float* out = (float*)d_out;
    unsigned char* ws = (unsigned char*)d_ws;

    hipLaunchKernelGGL(cheb_prep, dim3(41), dim3(64), 0, stream,
                       Tks, Theta, bias, ws);
    hipLaunchKernelGGL(cheb_main, dim3(NBLOCKS), dim3(256), 0, stream,
                       x, ws, out);
}